// Round 6
// baseline (537.254 us; speedup 1.0000x reference)
//
#include <hip/hip_runtime.h>
#include <hip/hip_bf16.h>

#define NEG_SLOPE 0.2f

typedef __bf16 bf16x8 __attribute__((ext_vector_type(8)));
typedef unsigned short u16x8 __attribute__((ext_vector_type(8)));
typedef float f32x4 __attribute__((ext_vector_type(4)));
typedef unsigned short ushort_t;

#define AS_GLOBAL(p) ((const __attribute__((address_space(1))) void*)(p))
#define AS_SHARED(p) ((__attribute__((address_space(3))) void*)(p))

__device__ inline ushort_t rne_bf16(float f) {
    unsigned u = __float_as_uint(f);
    return (ushort_t)((u + 0x7fffu + ((u >> 16) & 1u)) >> 16);
}

// ---------------------------------------------------------------------------
// CSR build: histogram of dst, parallel exclusive scan (+1 self-loop), fill
// ---------------------------------------------------------------------------

__global__ void khist(const int* __restrict__ dst, int E, int* __restrict__ counts) {
    int i = blockIdx.x * blockDim.x + threadIdx.x;
    if (i < E) atomicAdd(&counts[dst[i]], 1);
}

__global__ __launch_bounds__(1024) void kscan_part(const int* __restrict__ counts,
                                                   int* __restrict__ row_ptr,
                                                   int* __restrict__ bsum, int n) {
    __shared__ int wsum[16];
    int t = threadIdx.x, lane = t & 63, wid = t >> 6;
    int i = blockIdx.x * 1024 + t;
    int v = (i < n) ? (counts[i] + 1) : 0;
    int x = v;
    #pragma unroll
    for (int off = 1; off < 64; off <<= 1) {
        int y = __shfl_up(x, off, 64);
        if (lane >= off) x += y;
    }
    if (lane == 63) wsum[wid] = x;
    __syncthreads();
    if (wid == 0) {
        int ws = (lane < 16) ? wsum[lane] : 0;
        #pragma unroll
        for (int off = 1; off < 16; off <<= 1) {
            int y = __shfl_up(ws, off, 64);
            if (lane >= off) ws += y;
        }
        if (lane < 16) wsum[lane] = ws;
    }
    __syncthreads();
    int wave_excl = (wid == 0) ? 0 : wsum[wid - 1];
    if (i < n) row_ptr[i] = wave_excl + (x - v);
    if (t == 0) bsum[blockIdx.x] = wsum[15];
}

__global__ void kscan_tops(const int* __restrict__ bsum, int* __restrict__ boff,
                           int* __restrict__ row_ptr, int G, int n) {
    int lane = threadIdx.x;
    int v = (lane < G) ? bsum[lane] : 0;
    int x = v;
    #pragma unroll
    for (int off = 1; off < 64; off <<= 1) {
        int y = __shfl_up(x, off, 64);
        if (lane >= off) x += y;
    }
    if (lane < G) boff[lane] = x - v;
    if (lane == 63) row_ptr[n] = x;
}

__global__ void kscan_add(int* __restrict__ row_ptr, const int* __restrict__ boff,
                          int* __restrict__ cursor, int n) {
    int i = blockIdx.x * blockDim.x + threadIdx.x;
    if (i < n) {
        int r = row_ptr[i] + boff[i >> 10];
        row_ptr[i] = r;
        cursor[i] = r;
    }
}

__global__ void kfill(const int* __restrict__ src, const int* __restrict__ dst,
                      int E, int n, int* __restrict__ cursor, int* __restrict__ edge_src) {
    int i = blockIdx.x * blockDim.x + threadIdx.x;
    if (i < E) {
        int p = atomicAdd(&cursor[dst[i]], 1);
        edge_src[p] = src[i];
    } else if (i < E + n) {
        int v = i - E;
        int p = atomicAdd(&cursor[v], 1);
        edge_src[p] = v;
    }
}

// ---------------------------------------------------------------------------
// Weight prep: W_pre -> single bf16 plane (B-lo dropped; A keeps hi/lo split
// so GEMM1 = exact-fp32-A x bf16-B); W1 -> bf16. Both swizzled to MFMA-B-frag
// order: elem (k,n) -> ((k>>3)*Nn + n)*8 + (k&7).
// ---------------------------------------------------------------------------
__global__ void kprep(const float* __restrict__ Wpre, const float* __restrict__ W1,
                      ushort_t* __restrict__ PreH, ushort_t* __restrict__ W1b) {
    int i = blockIdx.x * blockDim.x + threadIdx.x;
    if (i < 1024 * 128) {
        int k = i >> 7, n = i & 127;
        int d = ((k >> 3) * 128 + n) * 8 + (k & 7);
        PreH[d] = rne_bf16(Wpre[i]);
    } else if (i < 1024 * 128 + 128 * 256) {
        int j2 = i - 1024 * 128;
        int k = j2 >> 8, n = j2 & 255;
        int d = ((k >> 3) * 256 + n) * 8 + (k & 7);
        W1b[d] = rne_bf16(W1[j2]);
    }
}

__device__ inline void split8(const float* v, bf16x8& hi, bf16x8& lo) {
    u16x8 h, l;
    #pragma unroll
    for (int i = 0; i < 8; ++i) {
        unsigned u = __float_as_uint(v[i]);
        h[i] = (ushort_t)(u >> 16);
        float lf = v[i] - __uint_as_float(u & 0xffff0000u);
        l[i] = (ushort_t)(__float_as_uint(lf) >> 16);
    }
    hi = __builtin_bit_cast(bf16x8, h);
    lo = __builtin_bit_cast(bf16x8, l);
}

// ---------------------------------------------------------------------------
// GEMM1: h0b(bf16) = relu(x @ W_pre + b_pre).  M x 1024 x 128.
// 32-row x 128-col block (4 waves; wave = 16 rows x 64 cols) for occupancy:
// grid ~1563 -> ~6 blocks/CU, LDS 16 KB. B bf16-only (16 KB/tile stage via
// global_load_lds); A fp32, split hi/lo in-register -> 2 MFMAs per fragment.
// ---------------------------------------------------------------------------
__global__ __launch_bounds__(256) void kgemm_mfma1(const float* __restrict__ A,
                                                   const ushort_t* __restrict__ Bhi,
                                                   const float* __restrict__ bias,
                                                   ushort_t* __restrict__ C, int M) {
    __shared__ __align__(16) ushort_t Bs[8192];   // [kc8][n128][j8] = 16 KB
    int t = threadIdx.x;
    int wid = t >> 6, lane = t & 63;
    int q = lane >> 4, l15 = lane & 15;
    int rh = wid & 1, ch = wid >> 1;              // row half, col half
    int m0 = blockIdx.x * 32 + rh * 16;
    int m = m0 + l15;
    const float* arow = A + (size_t)(m < M ? m : 0) * 1024;

    f32x4 acc[4];
    #pragma unroll
    for (int c = 0; c < 4; ++c) acc[c] = (f32x4){0.f, 0.f, 0.f, 0.f};

    float4 av[2][4];
    #pragma unroll
    for (int ks = 0; ks < 2; ++ks) {
        av[0][ks * 2]     = *(const float4*)(arow + ks * 32 + q * 8);
        av[0][ks * 2 + 1] = *(const float4*)(arow + ks * 32 + q * 8 + 4);
    }

    #pragma unroll 2
    for (int kt = 0; kt < 16; ++kt) {
        int cur = kt & 1, nxt = cur ^ 1;
        __syncthreads();  // barrier1: Bs readers of kt-1 done
        {   // async-stage 16 KB of B for this kt
            const ushort_t* sH = Bhi + kt * 8192;
            #pragma unroll
            for (int i = 0; i < 4; ++i) {
                int ge = (i * 256 + t) * 8;
                int le = (i * 256 + (t & 0xC0)) * 8;  // wave-uniform base
                __builtin_amdgcn_global_load_lds(AS_GLOBAL(sH + ge), AS_SHARED(Bs + le), 16, 0, 0);
            }
        }
        if (kt < 15) {  // prefetch A for kt+1 (in flight across this tile)
            const float* a2 = arow + (kt + 1) * 64;
            #pragma unroll
            for (int ks = 0; ks < 2; ++ks) {
                av[nxt][ks * 2]     = *(const float4*)(a2 + ks * 32 + q * 8);
                av[nxt][ks * 2 + 1] = *(const float4*)(a2 + ks * 32 + q * 8 + 4);
            }
        }
        __syncthreads();  // barrier2: drain -> Bs staged, av[cur] ready
        #pragma unroll
        for (int ks = 0; ks < 2; ++ks) {
            bf16x8 ah, al;
            split8((const float*)&av[cur][ks * 2], ah, al);
            int kc = ks * 4 + q;
            #pragma unroll
            for (int c = 0; c < 4; ++c) {
                bf16x8 bh = *(const bf16x8*)(Bs + (kc * 128 + ch * 64 + c * 16 + l15) * 8);
                acc[c] = __builtin_amdgcn_mfma_f32_16x16x32_bf16(ah, bh, acc[c], 0, 0, 0);
                acc[c] = __builtin_amdgcn_mfma_f32_16x16x32_bf16(al, bh, acc[c], 0, 0, 0);
            }
        }
    }
    // D layout: row = q*4 + r, col = c*16 + l15  [m89-verified]
    #pragma unroll
    for (int c = 0; c < 4; ++c) {
        int n = ch * 64 + c * 16 + l15;
        float bv = bias[n];
        #pragma unroll
        for (int r = 0; r < 4; ++r) {
            int mm = m0 + q * 4 + r;
            if (mm < M) C[(size_t)mm * 128 + n] = rne_bf16(fmaxf(acc[c][r] + bv, 0.f));
        }
    }
}

// ---------------------------------------------------------------------------
// GEMM2 + fused alpha1: h1b(bf16) = h0b @ W1b, single-bf16 MFMA.
// Block = 64 rows x 128 cols; g = blockIdx.y = column half = head.
// ---------------------------------------------------------------------------
__global__ __launch_bounds__(256) void kgemm_mfma2(const ushort_t* __restrict__ Ab,
                                                   const ushort_t* __restrict__ W1b,
                                                   const float* __restrict__ a_src,
                                                   const float* __restrict__ a_dst,
                                                   ushort_t* __restrict__ C,
                                                   float* __restrict__ as1,
                                                   float* __restrict__ ad1, int M) {
    __shared__ __align__(16) ushort_t Bs[16384];  // [kc16][n128][j8] = 32 KB
    int t = threadIdx.x;
    int wid = t >> 6, lane = t & 63;
    int q = lane >> 4, l15 = lane & 15;
    int g = blockIdx.y;
    int m0 = blockIdx.x * 64 + wid * 16;
    int m = m0 + l15;
    const ushort_t* arow = Ab + (size_t)(m < M ? m : 0) * 128;

    {   // stage W1b half (cols g*128..+127): 32 wave-chunks of 1 KB
        #pragma unroll
        for (int i = 0; i < 8; ++i) {
            int j = i * 4 + wid;
            int kc = j >> 1, hk = j & 1;
            int ge = ((kc * 256) + g * 128 + hk * 64 + lane) * 8;
            int le = j * 512;
            __builtin_amdgcn_global_load_lds(AS_GLOBAL(W1b + ge), AS_SHARED(Bs + le), 16, 0, 0);
        }
    }
    bf16x8 af[4];
    #pragma unroll
    for (int ks = 0; ks < 4; ++ks)
        af[ks] = *(const bf16x8*)(arow + ks * 32 + q * 8);
    __syncthreads();

    f32x4 acc[8];
    #pragma unroll
    for (int c = 0; c < 8; ++c) acc[c] = (f32x4){0.f, 0.f, 0.f, 0.f};

    #pragma unroll
    for (int ks = 0; ks < 4; ++ks) {
        int kc = ks * 4 + q;
        #pragma unroll
        for (int c = 0; c < 8; ++c) {
            bf16x8 b = *(const bf16x8*)(Bs + (kc * 128 + c * 16 + l15) * 8);
            acc[c] = __builtin_amdgcn_mfma_f32_16x16x32_bf16(af[ks], b, acc[c], 0, 0, 0);
        }
    }
    #pragma unroll
    for (int c = 0; c < 8; ++c) {
        int n = g * 128 + c * 16 + l15;
        #pragma unroll
        for (int r = 0; r < 4; ++r) {
            int mm = m0 + q * 4 + r;
            if (mm < M) C[(size_t)mm * 256 + n] = rne_bf16(acc[c][r]);
        }
    }
    // fused alpha: as1/ad1 for head g
    float asv[4] = {0.f, 0.f, 0.f, 0.f};
    float adv[4] = {0.f, 0.f, 0.f, 0.f};
    #pragma unroll
    for (int c = 0; c < 8; ++c) {
        float sa = a_src[g * 128 + c * 16 + l15];
        float da = a_dst[g * 128 + c * 16 + l15];
        #pragma unroll
        for (int r = 0; r < 4; ++r) {
            asv[r] += acc[c][r] * sa;
            adv[r] += acc[c][r] * da;
        }
    }
    #pragma unroll
    for (int off = 1; off <= 8; off <<= 1) {
        #pragma unroll
        for (int r = 0; r < 4; ++r) {
            asv[r] += __shfl_xor(asv[r], off, 64);
            adv[r] += __shfl_xor(adv[r], off, 64);
        }
    }
    if (l15 == 0) {
        #pragma unroll
        for (int r = 0; r < 4; ++r) {
            int node = m0 + q * 4 + r;
            if (node < M) {
                as1[node * 2 + g] = asv[r];
                ad1[node * 2 + g] = adv[r];
            }
        }
    }
}

// ---------------------------------------------------------------------------
// Aggregation layer 1 + fused layer-2 linear + alpha2.
// ---------------------------------------------------------------------------
__global__ __launch_bounds__(128) void kagg1(const ushort_t* __restrict__ h1b,
                                             const float* __restrict__ as1,
                                             const float* __restrict__ ad1,
                                             const float* __restrict__ b1,
                                             const float* __restrict__ W2,
                                             const float* __restrict__ a_src2,
                                             const float* __restrict__ a_dst2,
                                             const int* __restrict__ row_ptr,
                                             const int* __restrict__ edge_src,
                                             float* __restrict__ h2,
                                             float* __restrict__ as2,
                                             float* __restrict__ ad2, int n) {
    __shared__ float w_lds[128];   // [edge 64][head 2]
    __shared__ int   s_lds[64];
    __shared__ float red[2][4];
    int node = blockIdx.x;
    int t = threadIdx.x;
    int wid = t >> 6;
    int beg = row_ptr[node], end = row_ptr[node + 1];
    int h_ch = t >> 6;
    float advv = ad1[node * 2 + (t & 1)];
    float acc0 = 0.f, acc1 = 0.f, ssum = 0.f;
    for (int base = beg; base < end; base += 64) {
        int cnt = min(64, end - base);
        int i = t >> 1, h = t & 1;
        if (i < cnt) {
            int s = edge_src[base + i];
            float e = as1[s * 2 + h] + advv;
            e = (e > 0.f) ? e : NEG_SLOPE * e;
            w_lds[i * 2 + h] = __expf(e);
            if (h == 0) s_lds[i] = s;
        }
        __syncthreads();
        #pragma unroll 4
        for (int i2 = 0; i2 < cnt; ++i2) {
            float wv = w_lds[i2 * 2 + h_ch];
            int s = s_lds[i2];
            unsigned p = *(const unsigned*)(h1b + (size_t)s * 256 + t * 2);
            acc0 += wv * __uint_as_float(p << 16);
            acc1 += wv * __uint_as_float(p & 0xffff0000u);
            ssum += wv;
        }
        __syncthreads();
    }
    float inv = 1.f / (ssum + 1e-16f);
    float o0 = acc0 * inv + b1[t * 2];
    float o1 = acc1 * inv + b1[t * 2 + 1];
    o0 = (o0 > 0.f) ? o0 : (__expf(o0) - 1.f);
    o1 = (o1 > 0.f) ? o1 : (__expf(o1) - 1.f);
    float4 w0 = *(const float4*)(W2 + t * 8);
    float4 w1 = *(const float4*)(W2 + t * 8 + 4);
    float p0 = o0 * w0.x + o1 * w1.x;
    float p1 = o0 * w0.y + o1 * w1.y;
    float p2 = o0 * w0.z + o1 * w1.z;
    float p3 = o0 * w0.w + o1 * w1.w;
    #pragma unroll
    for (int off = 1; off < 64; off <<= 1) {
        p0 += __shfl_xor(p0, off, 64);
        p1 += __shfl_xor(p1, off, 64);
        p2 += __shfl_xor(p2, off, 64);
        p3 += __shfl_xor(p3, off, 64);
    }
    if ((t & 63) == 0) {
        red[wid][0] = p0; red[wid][1] = p1; red[wid][2] = p2; red[wid][3] = p3;
    }
    __syncthreads();
    if (t == 0) {
        float hv[4], s2 = 0.f, d2 = 0.f;
        #pragma unroll
        for (int j = 0; j < 4; ++j) {
            hv[j] = red[0][j] + red[1][j];
            h2[node * 4 + j] = hv[j];
            s2 += hv[j] * a_src2[j];
            d2 += hv[j] * a_dst2[j];
        }
        as2[node] = s2;
        ad2[node] = d2;
    }
}

// ---------------------------------------------------------------------------
// Aggregation layer 2 (1 head, C=4): wave per node, 16 edges in flight.
// ---------------------------------------------------------------------------
__global__ __launch_bounds__(256) void kagg2(const float* __restrict__ h2,
                                             const float* __restrict__ as2,
                                             const float* __restrict__ ad2,
                                             const float* __restrict__ b2,
                                             const int* __restrict__ row_ptr,
                                             const int* __restrict__ edge_src,
                                             float* __restrict__ out, int n) {
    int wid = threadIdx.x >> 6, lane = threadIdx.x & 63;
    int node = blockIdx.x * 4 + wid;
    if (node >= n) return;
    int beg = row_ptr[node], end = row_ptr[node + 1];
    int j = lane & 3, ig = lane >> 2;
    float adv = ad2[node];
    float acc = 0.f, ssum = 0.f;
    for (int p = beg + ig; p < end; p += 16) {
        int s = edge_src[p];
        float e = as2[s] + adv;
        e = (e > 0.f) ? e : NEG_SLOPE * e;
        float wv = __expf(e);
        acc += wv * h2[s * 4 + j];
        ssum += wv;
    }
    #pragma unroll
    for (int off = 32; off >= 4; off >>= 1) {
        acc += __shfl_down(acc, off);
        ssum += __shfl_down(ssum, off);
    }
    if (lane < 4) out[node * 4 + j] = acc / (ssum + 1e-16f) + b2[j];
}

// ---------------------------------------------------------------------------
extern "C" void kernel_launch(void* const* d_in, const int* in_sizes, int n_in,
                              void* d_out, int out_size, void* d_ws, size_t ws_size,
                              hipStream_t stream) {
    const float* x      = (const float*)d_in[0];
    const int*   ei     = (const int*)d_in[1];
    const float* W_pre  = (const float*)d_in[2];
    const float* b_pre  = (const float*)d_in[3];
    const float* W1     = (const float*)d_in[4];
    const float* a_src1 = (const float*)d_in[5];
    const float* a_dst1 = (const float*)d_in[6];
    const float* b1     = (const float*)d_in[7];
    const float* W2     = (const float*)d_in[8];
    const float* a_src2 = (const float*)d_in[9];
    const float* a_dst2 = (const float*)d_in[10];
    const float* b2     = (const float*)d_in[11];
    float* out = (float*)d_out;

    const int DIN = 1024;
    const int E = in_sizes[1] / 2;
    const int N = in_sizes[0] / DIN;

    const int* esrc = ei;
    const int* edst = ei + E;

    char* ws = (char*)d_ws;
    size_t off = 0;
    ushort_t* h1b = (ushort_t*)(ws + off); off += (size_t)N * 256 * 2;
    ushort_t* h0b = (ushort_t*)(ws + off); off += (size_t)N * 128 * 2;
    float* as1 = (float*)(ws + off);  off += (size_t)N * 2 * 4;
    float* ad1 = (float*)(ws + off);  off += (size_t)N * 2 * 4;
    float* h2  = (float*)(ws + off);  off += (size_t)N * 4 * 4;
    float* as2 = (float*)(ws + off);  off += (size_t)N * 4;
    float* ad2 = (float*)(ws + off);  off += (size_t)N * 4;
    int* row_ptr = (int*)(ws + off);  off += ((size_t)N + 16) * 4;
    int* cursor  = (int*)(ws + off);  off += (size_t)N * 4;
    int* counts  = (int*)(ws + off);  off += (size_t)N * 4;
    int* bsum    = (int*)(ws + off);  off += 64 * 4;
    int* boff    = (int*)(ws + off);  off += 64 * 4;
    int* edge_src = (int*)(ws + off); off += (size_t)(E + N) * 4;
    ushort_t* PreH = (ushort_t*)(ws + off); off += 1024 * 128 * 2;
    ushort_t* W1b  = (ushort_t*)(ws + off); off += 128 * 256 * 2;

    int G = (N + 1023) / 1024;

    // --- weight prep + CSR build ---
    kprep<<<640, 256, 0, stream>>>(W_pre, W1, PreH, W1b);
    hipMemsetAsync(counts, 0, (size_t)N * 4, stream);
    khist<<<(E + 255) / 256, 256, 0, stream>>>(edst, E, counts);
    kscan_part<<<G, 1024, 0, stream>>>(counts, row_ptr, bsum, N);
    kscan_tops<<<1, 64, 0, stream>>>(bsum, boff, row_ptr, G, N);
    kscan_add<<<(N + 255) / 256, 256, 0, stream>>>(row_ptr, boff, cursor, N);
    kfill<<<(E + N + 255) / 256, 256, 0, stream>>>(esrc, edst, E, N, cursor, edge_src);

    // --- h0b = relu(x @ W_pre + b_pre) : 32-row tiles for occupancy ---
    kgemm_mfma1<<<(N + 31) / 32, 256, 0, stream>>>(x, PreH, b_pre, h0b, N);
    // --- h1b = h0b @ W1b, + as1/ad1 fused ---
    {
        dim3 grid((N + 63) / 64, 2);
        kgemm_mfma2<<<grid, 256, 0, stream>>>(h0b, W1b, a_src1, a_dst1, h1b, as1, ad1, N);
    }
    // --- aggregate layer 1 + bias + elu + layer-2 linear + alpha2 (fused) ---
    kagg1<<<N, 128, 0, stream>>>(h1b, as1, ad1, b1, W2, a_src2, a_dst2,
                                 row_ptr, edge_src, h2, as2, ad2, N);
    // --- aggregate layer 2 + bias -> out ---
    kagg2<<<(N + 3) / 4, 256, 0, stream>>>(h2, as2, ad2, b2, row_ptr, edge_src, out, N);
}